// Round 3
// baseline (84.310 us; speedup 1.0000x reference)
//
#include <hip/hip_runtime.h>

#define EPSF 1e-8f
#define FPB 4      // frames per group
#define BLOCK 256
#define AT 4       // atoms per thread per chunk
#define NSPLIT 2   // grid = 1024*2 = 2048 blocks = 8 blocks/CU (full residency)

// readfirstlane: uniform value -> SGPR-resident float
__device__ inline float rf(float v) {
    return __int_as_float(__builtin_amdgcn_readfirstlane(__float_as_int(v)));
}

// Rigid frame from coords f,f+1,f+2: o[0..2]=origin, o[3..11]=rows e1,e2,e3
__device__ inline void compute_frame(const float* __restrict__ c, int f,
                                     float* __restrict__ o) {
    const float* p = c + 3 * f;
    float c0x = p[0], c0y = p[1], c0z = p[2];
    float c1x = p[3], c1y = p[4], c1z = p[5];
    float c2x = p[6], c2y = p[7], c2z = p[8];
    float e1x = c2x - c1x, e1y = c2y - c1y, e1z = c2z - c1z;
    float n1 = __builtin_amdgcn_sqrtf(e1x*e1x + e1y*e1y + e1z*e1z) + EPSF;
    float r1 = __builtin_amdgcn_rcpf(n1);
    e1x *= r1; e1y *= r1; e1z *= r1;
    float ax = c0x - c1x, ay = c0y - c1y, az = c0z - c1z;
    float d = ax*e1x + ay*e1y + az*e1z;
    ax -= d*e1x; ay -= d*e1y; az -= d*e1z;
    float n2 = __builtin_amdgcn_sqrtf(ax*ax + ay*ay + az*az) + EPSF;
    float r2 = __builtin_amdgcn_rcpf(n2);
    ax *= r2; ay *= r2; az *= r2;
    float bx = e1y*az - e1z*ay;
    float by = e1z*ax - e1x*az;
    float bz = e1x*ay - e1y*ax;
    o[0] = c1x; o[1]  = c1y; o[2]  = c1z;
    o[3] = e1x; o[4]  = e1y; o[5]  = e1z;
    o[6] = ax;  o[7]  = ay;  o[8]  = az;
    o[9] = bx;  o[10] = by;  o[11] = bz;
}

// ---------- Single kernel: frames in-block + hot loop + atomic finish ------
// fr-constants: v = o_p - M*o_t ; M = Rp^T*Rt.
// |Rp(p-o_p) - Rt(t-o_t)| == |(p - v) - M*t| since Rp is orthonormal.
// out[0] is memset to 0 by a graph memset node; each block adds its
// inv-scaled partial with one device-scope atomicAdd (2048 total, ~no
// contention). Nondeterminism ~1e-5 absolute, threshold is 1.98e-2.
__launch_bounds__(BLOCK, 8)
__global__ void fape_all(const float* __restrict__ pred,
                         const float* __restrict__ tru,
                         float* __restrict__ out,
                         int N, int F, float inv) {
    const int g = blockIdx.x >> 1;            // frame group (NSPLIT==2)
    const int s = blockIdx.x & (NSPLIT - 1);  // atom slice
    const int f0 = g * FPB;

    __shared__ float sfr[FPB][12];
    if (threadIdx.x < FPB) {
        const int f = f0 + threadIdx.x;
        float D[12];
        if (f < F) {
            float P[12], T[12], M[9];
            compute_frame(pred, f, P);
            compute_frame(tru,  f, T);
#pragma unroll
            for (int i = 0; i < 3; i++)
#pragma unroll
                for (int j = 0; j < 3; j++)
                    M[3*i+j] = P[3+i]*T[3+j] + P[6+i]*T[6+j] + P[9+i]*T[9+j];
            D[0] = P[0] - (M[0]*T[0] + M[1]*T[1] + M[2]*T[2]);
            D[1] = P[1] - (M[3]*T[0] + M[4]*T[1] + M[5]*T[2]);
            D[2] = P[2] - (M[6]*T[0] + M[7]*T[1] + M[8]*T[2]);
#pragma unroll
            for (int j = 0; j < 9; j++) D[3+j] = M[j];
        } else {
            // finite zero pad; masked by w=0 below
#pragma unroll
            for (int j = 0; j < 12; j++) D[j] = 0.0f;
        }
#pragma unroll
        for (int j = 0; j < 12; j++) sfr[threadIdx.x][j] = D[j];
    }
    __syncthreads();

    // 48 uniform constants -> SGPRs (same-address LDS reads broadcast, free)
    float C[FPB][12];
#pragma unroll
    for (int i = 0; i < FPB; i++)
#pragma unroll
        for (int j = 0; j < 12; j++)
            C[i][j] = rf(sfr[i][j]);

    float w[FPB], acc[FPB];
#pragma unroll
    for (int i = 0; i < FPB; i++) {
        w[i] = (f0 + i < F) ? 1.0f : 0.0f;   // uniform
        acc[i] = 0.0f;
    }

    const int span = N / NSPLIT;             // 2048 = 2 chunks of 1024
    const int base = s * span;
    float px[AT], py[AT], pz[AT], tx[AT], ty[AT], tz[AT];
    for (int c = 0; c < span; c += BLOCK * AT) {
#pragma unroll
        for (int a = 0; a < AT; a++) {
            int n = base + c + threadIdx.x + a * BLOCK;
            const float* pp = pred + 3 * n;
            px[a] = pp[0]; py[a] = pp[1]; pz[a] = pp[2];
            const float* tp = tru + 3 * n;
            tx[a] = tp[0]; ty[a] = tp[1]; tz[a] = tp[2];
        }
#pragma unroll
        for (int i = 0; i < FPB; i++) {
#pragma unroll
            for (int a = 0; a < AT; a++) {
                // c = (p - v) - M*t : 18 VALU ops/pair, 1 SGPR operand each
                float cx = fmaf(-C[i][3], tx[a], fmaf(-C[i][4], ty[a],
                             fmaf(-C[i][5], tz[a], px[a] - C[i][0])));
                float cy = fmaf(-C[i][6], tx[a], fmaf(-C[i][7], ty[a],
                             fmaf(-C[i][8], tz[a], py[a] - C[i][1])));
                float cz = fmaf(-C[i][9], tx[a], fmaf(-C[i][10], ty[a],
                             fmaf(-C[i][11], tz[a], pz[a] - C[i][2])));
                float d2 = fmaf(cz, cz, fmaf(cy, cy, fmaf(cx, cx, EPSF)));
                float dist = __builtin_amdgcn_sqrtf(d2);
                acc[i] += fminf(dist, 10.0f);
            }
        }
    }

    float t = 0.0f;
#pragma unroll
    for (int i = 0; i < FPB; i++) t = fmaf(w[i], acc[i], t);

    // wave reduce (64) -> cross-wave via LDS -> one atomicAdd per block
#pragma unroll
    for (int off = 32; off > 0; off >>= 1) t += __shfl_down(t, off, 64);
    __shared__ float sred[BLOCK / 64];
    const int lane = threadIdx.x & 63;
    if (lane == 0) sred[threadIdx.x >> 6] = t;
    __syncthreads();
    if (threadIdx.x == 0) {
        float z = 0.0f;
#pragma unroll
        for (int i = 0; i < BLOCK / 64; i++) z += sred[i];
        atomicAdd(out, z * inv);        // device scope: safe across XCDs
    }
}

extern "C" void kernel_launch(void* const* d_in, const int* in_sizes, int n_in,
                              void* d_out, int out_size, void* d_ws, size_t ws_size,
                              hipStream_t stream) {
    const float* pred = (const float*)d_in[0];
    const float* tru  = (const float*)d_in[1];
    float* out = (float*)d_out;

    int N = in_sizes[0] / 3;            // 4096
    int F = N - 2;                      // 4094
    int groups = (F + FPB - 1) / FPB;   // 1024
    int gridB = groups * NSPLIT;        // 2048 = 8 blocks/CU * 256 CU

    float inv = 1.0f / ((float)F * (float)N * 10.0f);

    // zero the accumulator (graph memset node; capture-safe, harness uses it)
    hipMemsetAsync(out, 0, sizeof(float), stream);

    fape_all<<<gridB, BLOCK, 0, stream>>>(pred, tru, out, N, F, inv);
}

// Round 4
// 70.826 us; speedup vs baseline: 1.1904x; 1.1904x over previous
//
#include <hip/hip_runtime.h>

#define EPSF 1e-8f
#define FPB 8      // frames per group (processed as 2 halves of 4)
#define HALF 4     // frames per constant batch (48 SGPR constants)
#define BLOCK 256
#define AT 4       // atoms per thread; span == BLOCK*AT -> whole slice in regs
#define NSPLIT 4   // grid = 512*4 = 2048 blocks = 8 blocks/CU (full residency)

// readfirstlane: uniform value -> SGPR-resident float
__device__ inline float rf(float v) {
    return __int_as_float(__builtin_amdgcn_readfirstlane(__float_as_int(v)));
}

// Rigid frame from coords f,f+1,f+2: o[0..2]=origin, o[3..11]=rows e1,e2,e3
__device__ inline void compute_frame(const float* __restrict__ c, int f,
                                     float* __restrict__ o) {
    const float* p = c + 3 * f;
    float c0x = p[0], c0y = p[1], c0z = p[2];
    float c1x = p[3], c1y = p[4], c1z = p[5];
    float c2x = p[6], c2y = p[7], c2z = p[8];
    float e1x = c2x - c1x, e1y = c2y - c1y, e1z = c2z - c1z;
    float n1 = __builtin_amdgcn_sqrtf(e1x*e1x + e1y*e1y + e1z*e1z) + EPSF;
    float r1 = __builtin_amdgcn_rcpf(n1);
    e1x *= r1; e1y *= r1; e1z *= r1;
    float ax = c0x - c1x, ay = c0y - c1y, az = c0z - c1z;
    float d = ax*e1x + ay*e1y + az*e1z;
    ax -= d*e1x; ay -= d*e1y; az -= d*e1z;
    float n2 = __builtin_amdgcn_sqrtf(ax*ax + ay*ay + az*az) + EPSF;
    float r2 = __builtin_amdgcn_rcpf(n2);
    ax *= r2; ay *= r2; az *= r2;
    float bx = e1y*az - e1z*ay;
    float by = e1z*ax - e1x*az;
    float bz = e1x*ay - e1y*ax;
    o[0] = c1x; o[1]  = c1y; o[2]  = c1z;
    o[3] = e1x; o[4]  = e1y; o[5]  = e1z;
    o[6] = ax;  o[7]  = ay;  o[8]  = az;
    o[9] = bx;  o[10] = by;  o[11] = bz;
}

// ---------- Kernel A: frames in-block + hot loop ---------------------------
// fr-constants: v = o_p - M*o_t ; M = Rp^T*Rt.
// |Rp(p-o_p) - Rt(t-o_t)| == |(p - v) - M*t| since Rp is orthonormal.
// FPB=8 halves redundant L2 atom traffic vs FPB=4 (traffic ~ groups*N).
// The 8 frames are consumed in 2 batches of 4 so only 48 uniform constants
// are SGPR-live at a time; the atom slice (span=1024) sits in 24 VGPRs.
__launch_bounds__(BLOCK, 8)
__global__ void fape_main(const float* __restrict__ pred,
                          const float* __restrict__ tru,
                          float* __restrict__ part, int N, int F) {
    const int g = blockIdx.x >> 2;            // frame group (NSPLIT==4)
    const int s = blockIdx.x & (NSPLIT - 1);  // atom slice
    const int f0 = g * FPB;

    __shared__ float sfr[FPB][12];
    if (threadIdx.x < FPB) {
        const int f = f0 + threadIdx.x;
        float D[12];
        if (f < F) {
            float P[12], T[12], M[9];
            compute_frame(pred, f, P);
            compute_frame(tru,  f, T);
#pragma unroll
            for (int i = 0; i < 3; i++)
#pragma unroll
                for (int j = 0; j < 3; j++)
                    M[3*i+j] = P[3+i]*T[3+j] + P[6+i]*T[6+j] + P[9+i]*T[9+j];
            D[0] = P[0] - (M[0]*T[0] + M[1]*T[1] + M[2]*T[2]);
            D[1] = P[1] - (M[3]*T[0] + M[4]*T[1] + M[5]*T[2]);
            D[2] = P[2] - (M[6]*T[0] + M[7]*T[1] + M[8]*T[2]);
#pragma unroll
            for (int j = 0; j < 9; j++) D[3+j] = M[j];
        } else {
            // finite zero pad; masked by w=0 below
#pragma unroll
            for (int j = 0; j < 12; j++) D[j] = 0.0f;
        }
#pragma unroll
        for (int j = 0; j < 12; j++) sfr[threadIdx.x][j] = D[j];
    }
    __syncthreads();

    const int span = N / NSPLIT;             // 1024 == BLOCK*AT
    const int base = s * span;
    float t = 0.0f;

    float px[AT], py[AT], pz[AT], tx[AT], ty[AT], tz[AT];
    for (int c = 0; c < span; c += BLOCK * AT) {   // executes once at N=4096
#pragma unroll
        for (int a = 0; a < AT; a++) {
            int n = base + c + threadIdx.x + a * BLOCK;
            const float* pp = pred + 3 * n;
            px[a] = pp[0]; py[a] = pp[1]; pz[a] = pp[2];
            const float* tp = tru + 3 * n;
            tx[a] = tp[0]; ty[a] = tp[1]; tz[a] = tp[2];
        }
#pragma unroll 1   // keep halves sequential: only 48 SGPR constants live
        for (int h = 0; h < FPB / HALF; h++) {
            // 48 uniform constants -> SGPRs (same-address LDS read broadcasts)
            float C[HALF][12];
#pragma unroll
            for (int i = 0; i < HALF; i++)
#pragma unroll
                for (int j = 0; j < 12; j++)
                    C[i][j] = rf(sfr[h * HALF + i][j]);

            float acc[HALF];
#pragma unroll
            for (int i = 0; i < HALF; i++) acc[i] = 0.0f;

#pragma unroll
            for (int i = 0; i < HALF; i++) {
#pragma unroll
                for (int a = 0; a < AT; a++) {
                    // c = (p - v) - M*t : 18 VALU ops/pair, 1 SGPR operand each
                    float cx = fmaf(-C[i][3], tx[a], fmaf(-C[i][4], ty[a],
                                 fmaf(-C[i][5], tz[a], px[a] - C[i][0])));
                    float cy = fmaf(-C[i][6], tx[a], fmaf(-C[i][7], ty[a],
                                 fmaf(-C[i][8], tz[a], py[a] - C[i][1])));
                    float cz = fmaf(-C[i][9], tx[a], fmaf(-C[i][10], ty[a],
                                 fmaf(-C[i][11], tz[a], pz[a] - C[i][2])));
                    float d2 = fmaf(cz, cz, fmaf(cy, cy, fmaf(cx, cx, EPSF)));
                    float dist = __builtin_amdgcn_sqrtf(d2);
                    acc[i] += fminf(dist, 10.0f);
                }
            }
#pragma unroll
            for (int i = 0; i < HALF; i++) {
                float wi = (f0 + h * HALF + i < F) ? 1.0f : 0.0f;  // uniform
                t = fmaf(wi, acc[i], t);
            }
        }
    }

    // wave reduce (64) -> cross-wave via LDS -> one plain store per block
#pragma unroll
    for (int off = 32; off > 0; off >>= 1) t += __shfl_down(t, off, 64);
    __shared__ float sred[BLOCK / 64];
    const int lane = threadIdx.x & 63;
    if (lane == 0) sred[threadIdx.x >> 6] = t;
    __syncthreads();
    if (threadIdx.x == 0) {
        float z = 0.0f;
#pragma unroll
        for (int i = 0; i < BLOCK / 64; i++) z += sred[i];
        part[blockIdx.x] = z;           // no atomics: deterministic partials
    }
}

// ---------- Kernel B: reduce 2048 partials, write the scalar ---------------
__global__ void reduce_kernel(const float* __restrict__ part,
                              float* __restrict__ out, int nb, float inv) {
    float s = 0.0f;
    for (int i = threadIdx.x; i < nb; i += BLOCK) s += part[i];
#pragma unroll
    for (int off = 32; off > 0; off >>= 1) s += __shfl_down(s, off, 64);
    __shared__ float sred[BLOCK / 64];
    const int lane = threadIdx.x & 63;
    if (lane == 0) sred[threadIdx.x >> 6] = s;
    __syncthreads();
    if (threadIdx.x == 0) {
        float z = 0.0f;
#pragma unroll
        for (int i = 0; i < BLOCK / 64; i++) z += sred[i];
        out[0] = z * inv;               // overwrites poison; no memset needed
    }
}

extern "C" void kernel_launch(void* const* d_in, const int* in_sizes, int n_in,
                              void* d_out, int out_size, void* d_ws, size_t ws_size,
                              hipStream_t stream) {
    const float* pred = (const float*)d_in[0];
    const float* tru  = (const float*)d_in[1];
    float* out = (float*)d_out;

    int N = in_sizes[0] / 3;            // 4096
    int F = N - 2;                      // 4094
    int groups = (F + FPB - 1) / FPB;   // 512
    int gridB = groups * NSPLIT;        // 2048 = 8 blocks/CU * 256 CU

    float* part = (float*)d_ws;         // gridB floats

    fape_main<<<gridB, BLOCK, 0, stream>>>(pred, tru, part, N, F);

    float inv = 1.0f / ((float)F * (float)N * 10.0f);
    reduce_kernel<<<1, BLOCK, 0, stream>>>(part, out, gridB, inv);
}

// Round 5
// 67.930 us; speedup vs baseline: 1.2411x; 1.0426x over previous
//
#include <hip/hip_runtime.h>

#define EPSF 1e-8f
#define FPB 4      // frames per group
#define BLOCK 256
#define AT 4       // contiguous atoms per thread -> 3x float4 loads per array
#define NSPLIT 2   // grid = 1024*2 = 2048 blocks = 8 blocks/CU (full residency)

// readfirstlane: uniform value -> SGPR-resident float
__device__ inline float rf(float v) {
    return __int_as_float(__builtin_amdgcn_readfirstlane(__float_as_int(v)));
}

// Rigid frame from coords f,f+1,f+2: o[0..2]=origin, o[3..11]=rows e1,e2,e3
__device__ inline void compute_frame(const float* __restrict__ c, int f,
                                     float* __restrict__ o) {
    const float* p = c + 3 * f;
    float c0x = p[0], c0y = p[1], c0z = p[2];
    float c1x = p[3], c1y = p[4], c1z = p[5];
    float c2x = p[6], c2y = p[7], c2z = p[8];
    float e1x = c2x - c1x, e1y = c2y - c1y, e1z = c2z - c1z;
    float n1 = __builtin_amdgcn_sqrtf(e1x*e1x + e1y*e1y + e1z*e1z) + EPSF;
    float r1 = __builtin_amdgcn_rcpf(n1);
    e1x *= r1; e1y *= r1; e1z *= r1;
    float ax = c0x - c1x, ay = c0y - c1y, az = c0z - c1z;
    float d = ax*e1x + ay*e1y + az*e1z;
    ax -= d*e1x; ay -= d*e1y; az -= d*e1z;
    float n2 = __builtin_amdgcn_sqrtf(ax*ax + ay*ay + az*az) + EPSF;
    float r2 = __builtin_amdgcn_rcpf(n2);
    ax *= r2; ay *= r2; az *= r2;
    float bx = e1y*az - e1z*ay;
    float by = e1z*ax - e1x*az;
    float bz = e1x*ay - e1y*ax;
    o[0] = c1x; o[1]  = c1y; o[2]  = c1z;
    o[3] = e1x; o[4]  = e1y; o[5]  = e1z;
    o[6] = ax;  o[7]  = ay;  o[8]  = az;
    o[9] = bx;  o[10] = by;  o[11] = bz;
}

// ---------- Kernel A (fused): frames in-block + hot loop --------------------
// fr-constants: v = o_p - M*o_t ; M = Rp^T*Rt.
// |Rp(p-o_p) - Rt(t-o_t)| == |(p - v) - M*t| since Rp is orthonormal.
// Each thread owns AT=4 CONTIGUOUS atoms: 12 floats/array = 3 float4 loads
// (16B aligned: byte off = 48*tid + 12288*k). VMEM instrs per chunk 24 -> 6.
__launch_bounds__(BLOCK, 8)
__global__ void fape_main(const float* __restrict__ pred,
                          const float* __restrict__ tru,
                          float* __restrict__ part, int N, int F) {
    const int g = blockIdx.x >> 1;            // frame group (NSPLIT==2)
    const int s = blockIdx.x & (NSPLIT - 1);  // atom slice
    const int f0 = g * FPB;

    __shared__ float sfr[FPB][12];
    if (threadIdx.x < FPB) {
        const int f = f0 + threadIdx.x;
        float D[12];
        if (f < F) {
            float P[12], T[12], M[9];
            compute_frame(pred, f, P);
            compute_frame(tru,  f, T);
#pragma unroll
            for (int i = 0; i < 3; i++)
#pragma unroll
                for (int j = 0; j < 3; j++)
                    M[3*i+j] = P[3+i]*T[3+j] + P[6+i]*T[6+j] + P[9+i]*T[9+j];
            D[0] = P[0] - (M[0]*T[0] + M[1]*T[1] + M[2]*T[2]);
            D[1] = P[1] - (M[3]*T[0] + M[4]*T[1] + M[5]*T[2]);
            D[2] = P[2] - (M[6]*T[0] + M[7]*T[1] + M[8]*T[2]);
#pragma unroll
            for (int j = 0; j < 9; j++) D[3+j] = M[j];
        } else {
            // finite zero pad; masked by w=0 below
#pragma unroll
            for (int j = 0; j < 12; j++) D[j] = 0.0f;
        }
#pragma unroll
        for (int j = 0; j < 12; j++) sfr[threadIdx.x][j] = D[j];
    }
    __syncthreads();

    // 48 uniform constants -> SGPRs (same-address LDS reads broadcast, free)
    float C[FPB][12];
#pragma unroll
    for (int i = 0; i < FPB; i++)
#pragma unroll
        for (int j = 0; j < 12; j++)
            C[i][j] = rf(sfr[i][j]);

    float w[FPB], acc[FPB];
#pragma unroll
    for (int i = 0; i < FPB; i++) {
        w[i] = (f0 + i < F) ? 1.0f : 0.0f;   // uniform
        acc[i] = 0.0f;
    }

    const int span = N / NSPLIT;             // 2048 = 2 chunks of 1024
    const int base = s * span;
    for (int c = 0; c < span; c += BLOCK * AT) {
        const int n0 = base + c + threadIdx.x * AT;   // 4 contiguous atoms
        const float4* P4 = (const float4*)(pred + 3 * n0);
        const float4* T4 = (const float4*)(tru  + 3 * n0);
        float4 pa = P4[0], pb = P4[1], pc = P4[2];
        float4 ta = T4[0], tb = T4[1], tc = T4[2];
        // unpack (register renaming only)
        float px[AT] = { pa.x, pa.w, pb.z, pc.y };
        float py[AT] = { pa.y, pb.x, pb.w, pc.z };
        float pz[AT] = { pa.z, pb.y, pc.x, pc.w };
        float tx[AT] = { ta.x, ta.w, tb.z, tc.y };
        float ty[AT] = { ta.y, tb.x, tb.w, tc.z };
        float tz[AT] = { ta.z, tb.y, tc.x, tc.w };
#pragma unroll
        for (int i = 0; i < FPB; i++) {
#pragma unroll
            for (int a = 0; a < AT; a++) {
                // c = (p - v) - M*t : 18 VALU ops/pair, 1 SGPR operand each
                float cx = fmaf(-C[i][3], tx[a], fmaf(-C[i][4], ty[a],
                             fmaf(-C[i][5], tz[a], px[a] - C[i][0])));
                float cy = fmaf(-C[i][6], tx[a], fmaf(-C[i][7], ty[a],
                             fmaf(-C[i][8], tz[a], py[a] - C[i][1])));
                float cz = fmaf(-C[i][9], tx[a], fmaf(-C[i][10], ty[a],
                             fmaf(-C[i][11], tz[a], pz[a] - C[i][2])));
                float d2 = fmaf(cz, cz, fmaf(cy, cy, fmaf(cx, cx, EPSF)));
                float dist = __builtin_amdgcn_sqrtf(d2);
                acc[i] += fminf(dist, 10.0f);
            }
        }
    }

    float t = 0.0f;
#pragma unroll
    for (int i = 0; i < FPB; i++) t = fmaf(w[i], acc[i], t);

    // wave reduce (64) -> cross-wave via LDS -> one plain store per block
#pragma unroll
    for (int off = 32; off > 0; off >>= 1) t += __shfl_down(t, off, 64);
    __shared__ float sred[BLOCK / 64];
    const int lane = threadIdx.x & 63;
    if (lane == 0) sred[threadIdx.x >> 6] = t;
    __syncthreads();
    if (threadIdx.x == 0) {
        float z = 0.0f;
#pragma unroll
        for (int i = 0; i < BLOCK / 64; i++) z += sred[i];
        part[blockIdx.x] = z;           // no atomics: deterministic partials
    }
}

// ---------- Kernel B: reduce 2048 partials, write the scalar ---------------
__global__ void reduce_kernel(const float* __restrict__ part,
                              float* __restrict__ out, int nb, float inv) {
    float s = 0.0f;
    for (int i = threadIdx.x; i < nb; i += BLOCK) s += part[i];
#pragma unroll
    for (int off = 32; off > 0; off >>= 1) s += __shfl_down(s, off, 64);
    __shared__ float sred[BLOCK / 64];
    const int lane = threadIdx.x & 63;
    if (lane == 0) sred[threadIdx.x >> 6] = s;
    __syncthreads();
    if (threadIdx.x == 0) {
        float z = 0.0f;
#pragma unroll
        for (int i = 0; i < BLOCK / 64; i++) z += sred[i];
        out[0] = z * inv;               // overwrites poison; no memset needed
    }
}

extern "C" void kernel_launch(void* const* d_in, const int* in_sizes, int n_in,
                              void* d_out, int out_size, void* d_ws, size_t ws_size,
                              hipStream_t stream) {
    const float* pred = (const float*)d_in[0];
    const float* tru  = (const float*)d_in[1];
    float* out = (float*)d_out;

    int N = in_sizes[0] / 3;            // 4096
    int F = N - 2;                      // 4094
    int groups = (F + FPB - 1) / FPB;   // 1024
    int gridB = groups * NSPLIT;        // 2048 = 8 blocks/CU * 256 CU

    float* part = (float*)d_ws;         // gridB floats

    fape_main<<<gridB, BLOCK, 0, stream>>>(pred, tru, part, N, F);

    float inv = 1.0f / ((float)F * (float)N * 10.0f);
    reduce_kernel<<<1, BLOCK, 0, stream>>>(part, out, gridB, inv);
}